// Round 2
// baseline (540.022 us; speedup 1.0000x reference)
//
#include <hip/hip_runtime.h>

// ---------------------------------------------------------------------------
// ASA (AdaAttN-style) fused pipeline for MI355X / gfx950
// B=4, C=256, H=W=64 -> N=M=4096 tokens.
//
// R11 (= R10 de-risked + T5):
//  * T14 async-stage: next K/V tile global loads issued into VGPRs right
//    after current tile's ds_writes; barriers are lgkmcnt(0)+raw s_barrier
//    so prefetch vmcnt loads are never drained at a barrier.
//  * T12 in-register P: S^T fragments -> PV A-fragments via
//    __builtin_amdgcn_permlane32_swap (asm fallback if builtin missing).
//    Psw LDS buffer + round-trip deleted.
//  * T13 defer-max (THR=8 nats): skip accumulator rescale when
//    __all(mt - mrow <= 8); P bounded by e^8, fine in f16.
//  * T5: s_setprio(1) around QK^T and PV MFMA clusters.
//  * Tree max/sum reductions (depth 5) instead of 31-deep serial chains.
//
//  ws + 0      : cm [1024] f32      ws + 4096  : cr [1024] f32
//  ws + 8192   : Wb [3*65536] fp16
//  ws + 1 MiB  : A  8 MiB fp16  Qt
//  ws + 9 MiB  : Bv 8 MiB fp16  Vt [c][tok]
//  ws + 17 MiB : Cc 8 MiB fp16  Xk -> Kt (in-place)
//  d_out lo/hi : X1 (style^T), X2 (ckey^T) scratch
// ---------------------------------------------------------------------------

typedef unsigned int u32;
typedef unsigned short u16;
typedef _Float16 f16x8 __attribute__((ext_vector_type(8)));
typedef float f32x4 __attribute__((ext_vector_type(4)));
typedef float f32x16 __attribute__((ext_vector_type(16)));
typedef unsigned int u32x2 __attribute__((ext_vector_type(2)));

#define L2E 1.44269504088896340736f
#define MFMA(a, b, c) __builtin_amdgcn_mfma_f32_16x16x32_f16(a, b, c, 0, 0, 0)
#define MFMA32(a, b, c) __builtin_amdgcn_mfma_f32_32x32x16_f16(a, b, c, 0, 0, 0)
#define EXP2(x) __builtin_amdgcn_exp2f(x)

__device__ __forceinline__ u16 h_bits(_Float16 h) { return __builtin_bit_cast(u16, h); }
__device__ __forceinline__ u16 f2h(float f) { return h_bits((_Float16)f); }
__device__ __forceinline__ u32 pk2(float a, float b) {
    return (u32)f2h(a) | ((u32)f2h(b) << 16);
}

__device__ __forceinline__ f16x8 ldh8(const u16* p) {
    uint4 v = *(const uint4*)p;
    return __builtin_bit_cast(f16x8, v);
}

// lane i<32: r.x = a[i],    r.y = a[i+32]
// lane i>=32: r.x = b[i-32], r.y = b[i]
__device__ __forceinline__ u32x2 pl32_swap(u32 a, u32 b) {
#if __has_builtin(__builtin_amdgcn_permlane32_swap)
    return __builtin_amdgcn_permlane32_swap(a, b, false, false);
#else
    asm("v_permlane32_swap_b32 %0, %1" : "+v"(a), "+v"(b));
    u32x2 r; r.x = a; r.y = b; return r;
#endif
}

// barrier that does NOT drain vmcnt (keeps prefetch loads in flight).
// lgkmcnt(0) makes this wave's LDS writes/reads complete before signaling.
__device__ __forceinline__ void barrier_nv() {
    asm volatile("s_waitcnt lgkmcnt(0)" ::: "memory");
    __builtin_amdgcn_s_barrier();
    asm volatile("" ::: "memory");
}

// ---------------- content stats: mean & rstd per (b,c) ---------------------
__global__ void k_stats(const float* __restrict__ content,
                        float* __restrict__ cm, float* __restrict__ cr) {
    int blk = blockIdx.x;                       // 0..1023 = b*256+c
    const float* p = content + (size_t)blk * 4096;
    int t = threadIdx.x;
    float s = 0.f, ss = 0.f;
    for (int i = 0; i < 4; i++) {
        float4 v = *(const float4*)(p + (i * 256 + t) * 4);
        s  += (v.x + v.y) + (v.z + v.w);
        ss += (v.x * v.x + v.y * v.y) + (v.z * v.z + v.w * v.w);
    }
    for (int d = 32; d >= 1; d >>= 1) { s += __shfl_xor(s, d); ss += __shfl_xor(ss, d); }
    __shared__ __align__(16) float as[4], ass[4];
    int w = t >> 6;
    if ((t & 63) == 0) { as[w] = s; ass[w] = ss; }
    __syncthreads();
    if (t == 0) {
        s  = (as[0] + as[1]) + (as[2] + as[3]);
        ss = (ass[0] + ass[1]) + (ass[2] + ass[3]);
        float mean = s * (1.0f / 4096.0f);
        float var = (ss - s * mean) * (1.0f / 4095.0f);   // unbiased (ddof=1)
        cm[blk] = mean;
        cr[blk] = rsqrtf(var + 1e-5f);
    }
}

// ---------------- prep: 3 transposes + weight cvt in ONE launch ------------
// z 0..3: style->X1 ; 4..7: ckey->X2 ; 8..11: skey->Cc ; 12..14: weights
__global__ void k_prep(const float* __restrict__ style, const float* __restrict__ ckey,
                       const float* __restrict__ skey,
                       const float* __restrict__ Wf, const float* __restrict__ Wg,
                       const float* __restrict__ Wh,
                       u16* __restrict__ X1, u16* __restrict__ X2, u16* __restrict__ Cc,
                       u16* __restrict__ Wb) {
    int z = blockIdx.z, t = threadIdx.x;
    if (z >= 12) {
        if (blockIdx.y != 0) return;
        int m = z - 12;
        const float* src = (m == 0) ? Wf : ((m == 1) ? Wg : Wh);
        u16* dst = Wb + m * 65536;
        int i = (blockIdx.x * 256 + t) * 4;
        float4 v = *(const float4*)(src + i);
        ushort4 o;
        o.x = f2h(v.x); o.y = f2h(v.y); o.z = f2h(v.z); o.w = f2h(v.w);
        *(ushort4*)(dst + i) = o;
        return;
    }
    int tensor = z >> 2, b = z & 3;
    const float* src = ((tensor == 0) ? style : ((tensor == 1) ? ckey : skey))
                       + (size_t)b * 256 * 4096;
    u16* dst = ((tensor == 0) ? X1 : ((tensor == 1) ? X2 : Cc)) + (size_t)b * 4096 * 256;
    int c0 = blockIdx.y * 64, t0 = blockIdx.x * 64;
    __shared__ __align__(16) float ls[64][65];
    int tr = t >> 4, tc = t & 15;
    for (int i = 0; i < 4; i++) {
        int c_off = i * 16 + tr;
        float4 v = *(const float4*)(src + (size_t)(c0 + c_off) * 4096 + t0 + tc * 4);
        ls[tc * 4 + 0][c_off] = v.x;
        ls[tc * 4 + 1][c_off] = v.y;
        ls[tc * 4 + 2][c_off] = v.z;
        ls[tc * 4 + 3][c_off] = v.w;
    }
    __syncthreads();
    for (int i = 0; i < 4; i++) {
        int tokrow = i * 16 + tr;
        ushort4 o;
        o.x = f2h(ls[tokrow][tc * 4 + 0]);
        o.y = f2h(ls[tokrow][tc * 4 + 1]);
        o.z = f2h(ls[tokrow][tc * 4 + 2]);
        o.w = f2h(ls[tokrow][tc * 4 + 3]);
        *(ushort4*)(dst + (size_t)(t0 + tokrow) * 256 + c0 + tc * 4) = o;
    }
}

// ---------------- all three conv1x1 GEMMs, one launch -----------------------
// mode 0: Q = X2*Wf^T + bf -> A (token-major)
// mode 1: K = Cc*Wg^T + bg -> Cc (in-place, token-major)
// mode 2: V = Wh*X1 + bh   -> Bv (channel-major)
__launch_bounds__(256, 2)
__global__ void k_gemm(const u16* X1, const u16* X2, u16* Cc,
                       u16* A, u16* Bv, const u16* __restrict__ Wb,
                       const float* __restrict__ bfp, const float* __restrict__ bgp,
                       const float* __restrict__ bhp) {
    int mode = blockIdx.z, b = blockIdx.y, tok0 = blockIdx.x * 128;
    const u16* X = ((mode == 0) ? X2 : ((mode == 1) ? (const u16*)Cc : X1))
                   + (size_t)b * 4096 * 256;
    const u16* W = Wb + mode * 65536;
    const float* bias = (mode == 0) ? bfp : ((mode == 1) ? bgp : bhp);
    __shared__ __align__(16) u16 wt[256 * 40];
    int t = threadIdx.x, w = t >> 6, lane = t & 63, ln = lane & 15, quad = lane >> 4;

    f32x4 acc[8][4];
    for (int i = 0; i < 8; i++)
        for (int j = 0; j < 4; j++) acc[i][j] = f32x4{0.f, 0.f, 0.f, 0.f};

    for (int ks = 0; ks < 8; ks++) {
        {   // stage W[o = t][ks*32 .. +32) -> LDS : full 64 B per row
            const u16* wr = W + t * 256 + ks * 32;
            uint4 w0 = *(const uint4*)(wr + 0);
            uint4 w1 = *(const uint4*)(wr + 8);
            uint4 w2 = *(const uint4*)(wr + 16);
            uint4 w3 = *(const uint4*)(wr + 24);
            *(uint4*)(wt + t * 40 + 0)  = w0;
            *(uint4*)(wt + t * 40 + 8)  = w1;
            *(uint4*)(wt + t * 40 + 16) = w2;
            *(uint4*)(wt + t * 40 + 24) = w3;
        }
        __syncthreads();
        f16x8 wf[4];
        #pragma unroll
        for (int ct = 0; ct < 4; ct++)
            wf[ct] = ldh8(wt + (w * 64 + ct * 16 + ln) * 40 + quad * 8);
        #pragma unroll
        for (int rt = 0; rt < 8; rt++) {
            f16x8 xf = ldh8(X + (size_t)(tok0 + rt * 16 + ln) * 256 + ks * 32 + quad * 8);
            if (mode < 2) {
                #pragma unroll
                for (int ct = 0; ct < 4; ct++) acc[rt][ct] = MFMA(xf, wf[ct], acc[rt][ct]);
            } else {
                #pragma unroll
                for (int ct = 0; ct < 4; ct++) acc[rt][ct] = MFMA(wf[ct], xf, acc[rt][ct]);
            }
        }
        __syncthreads();
    }

    if (mode < 2) {
        u16* O = ((mode == 0) ? A : Cc) + (size_t)b * 4096 * 256;
        float bv[4];
        #pragma unroll
        for (int ct = 0; ct < 4; ct++) bv[ct] = bias[w * 64 + ct * 16 + ln];
        #pragma unroll
        for (int rt = 0; rt < 8; rt++)
            #pragma unroll
            for (int ct = 0; ct < 4; ct++)
                #pragma unroll
                for (int r = 0; r < 4; r++) {
                    int tok = tok0 + rt * 16 + quad * 4 + r;
                    int o = w * 64 + ct * 16 + ln;
                    O[(size_t)tok * 256 + o] = f2h(acc[rt][ct][r] + bv[ct]);
                }
    } else {
        u16* OV = Bv + (size_t)b * 256 * 4096;
        #pragma unroll
        for (int ct = 0; ct < 4; ct++)
            #pragma unroll
            for (int r = 0; r < 4; r++) {
                int o = w * 64 + ct * 16 + quad * 4 + r;
                float bb = bias[o];
                #pragma unroll
                for (int rt = 0; rt < 8; rt++) {
                    int tok = tok0 + rt * 16 + ln;
                    OV[(size_t)o * 4096 + tok] = f2h(acc[rt][ct][r] + bb);
                }
            }
    }
}

// ---------------- flash attention + fused AdaIN epilogue -------------------
// grid: (32 q-tiles of 128, 4 batch, 4 c-quarters) = 512 blocks = 2/CU.
// Wave owns 32 q-rows; m-tile 64. V^2 hi/lo from the V fragment in-register.
__launch_bounds__(256, 2)
__global__ void k_flash(const u16* __restrict__ Qt, const u16* __restrict__ Kt,
                        const u16* __restrict__ Vt,
                        const float* __restrict__ content, const float* __restrict__ cm,
                        const float* __restrict__ cr, float* __restrict__ out) {
    __shared__ __align__(16) char smem[67584];
    u16* Ks = (u16*)smem;                    // [64 tok][264]  33792 B
    u16* Vs = (u16*)(smem + 33792);          // [64 c][72]      9216 B
    int t = threadIdx.x, w = t >> 6, l = t & 63, lq = l & 31, h = l >> 5;

    int b = blockIdx.y, q0 = blockIdx.x * 128, coff = blockIdx.z * 64;

    // Q as B-operand fragments, pinned: col q = lq, k = h*8+j (+16ks)
    f16x8 qf[16];
    {
        const u16* qp = Qt + ((size_t)b * 4096 + q0 + w * 32 + lq) * 256 + h * 8;
        #pragma unroll
        for (int ks = 0; ks < 16; ks++) qf[ks] = ldh8(qp + ks * 16);
    }

    f32x16 am[2], aq[2];
    #pragma unroll
    for (int i = 0; i < 16; i++) { am[0][i] = 0.f; am[1][i] = 0.f; aq[0][i] = 0.f; aq[1][i] = 0.f; }
    float mrow = -1e30f, lrow = 0.f;

    const u16* Kg = Kt + (size_t)b * 4096 * 256;
    const u16* Vg = Vt + ((size_t)b * 256 + coff) * 4096;

    // ---- T14 prologue: prefetch tile 0 into registers ----
    uint4 kr[8], vr[2];
    #pragma unroll
    for (int i = 0; i < 8; i++) {
        int e = i * 256 + t;
        kr[i] = *(const uint4*)(Kg + (size_t)(e >> 5) * 256 + (e & 31) * 8);
    }
    #pragma unroll
    for (int i = 0; i < 2; i++) {
        int e = i * 256 + t;
        vr[i] = *(const uint4*)(Vg + (size_t)(e >> 3) * 4096 + (e & 7) * 8);
    }

    for (int it = 0; it < 64; it++) {
        // write staged tile regs -> LDS (vmcnt wait auto-inserted here; by
        // now the loads have had a full compute phase to land)
        #pragma unroll
        for (int i = 0; i < 8; i++) {
            int e = i * 256 + t;
            *(uint4*)(Ks + (e >> 5) * 264 + (e & 31) * 8) = kr[i];
        }
        #pragma unroll
        for (int i = 0; i < 2; i++) {
            int e = i * 256 + t;
            *(uint4*)(Vs + (e >> 3) * 72 + (e & 7) * 8) = vr[i];
        }
        // issue next tile's loads; they stay in flight across both barriers
        if (it < 63) {
            int m0n = (it + 1) * 64;
            #pragma unroll
            for (int i = 0; i < 8; i++) {
                int e = i * 256 + t;
                kr[i] = *(const uint4*)(Kg + (size_t)(m0n + (e >> 5)) * 256 + (e & 31) * 8);
            }
            #pragma unroll
            for (int i = 0; i < 2; i++) {
                int e = i * 256 + t;
                vr[i] = *(const uint4*)(Vg + (size_t)(e >> 3) * 4096 + m0n + (e & 7) * 8);
            }
        }
        barrier_nv();

        // S^T[m][q] = K * Q^T   (two 32-row m-tiles)
        f32x16 s0, s1;
        #pragma unroll
        for (int i = 0; i < 16; i++) { s0[i] = 0.f; s1[i] = 0.f; }
        __builtin_amdgcn_s_setprio(1);
        #pragma unroll
        for (int ks = 0; ks < 16; ks++) {
            f16x8 k0 = ldh8(Ks + lq * 264 + ks * 16 + h * 8);
            s0 = MFMA32(k0, qf[ks], s0);
            f16x8 k1 = ldh8(Ks + (32 + lq) * 264 + ks * 16 + h * 8);
            s1 = MFMA32(k1, qf[ks], s1);
        }
        __builtin_amdgcn_s_setprio(0);

        // online softmax over m: tree max (depth 5) + one shfl_xor(32)
        float m8[8];
        #pragma unroll
        for (int r = 0; r < 8; r++)
            m8[r] = fmaxf(fmaxf(s0[r], s0[r + 8]), fmaxf(s1[r], s1[r + 8]));
        #pragma unroll
        for (int d = 4; d >= 1; d >>= 1)
            #pragma unroll
            for (int r = 0; r < d; r++) m8[r] = fmaxf(m8[r], m8[r + d]);
        float mt = fmaxf(m8[0], __shfl_xor(m8[0], 32));

        // T13 defer-max: only advance the running max (and rescale the
        // accumulators) when some row grew by > 8 nats. P <= e^8 fits f16.
        float mn, al;
        bool resc = !__all(mt - mrow <= 8.0f);
        if (resc) {
            mn = fmaxf(mrow, mt);
            al = EXP2((mrow - mn) * L2E);
            mrow = mn;
        } else {
            mn = mrow;
            al = 1.0f;
        }
        float base = mn * L2E;
        #pragma unroll
        for (int r = 0; r < 16; r++) {
            float p0 = (float)(_Float16)EXP2(__builtin_fmaf(s0[r], L2E, -base));
            float p1 = (float)(_Float16)EXP2(__builtin_fmaf(s1[r], L2E, -base));
            s0[r] = p0; s1[r] = p1;
        }
        float a8[8];
        #pragma unroll
        for (int r = 0; r < 8; r++)
            a8[r] = (s0[r] + s0[r + 8]) + (s1[r] + s1[r + 8]);
        #pragma unroll
        for (int d = 4; d >= 1; d >>= 1)
            #pragma unroll
            for (int r = 0; r < d; r++) a8[r] += a8[r + d];
        float rs = a8[0] + __shfl_xor(a8[0], 32);
        lrow = lrow * al + rs;

        if (resc) {
            // rescale accumulators; alpha of q broadcast via shfl
            #pragma unroll
            for (int r = 0; r < 16; r++) {
                float sc = __shfl(al, 8 * (r >> 2) + 4 * h + (r & 3));
                am[0][r] *= sc; am[1][r] *= sc;
                aq[0][r] *= sc; aq[1][r] *= sc;
            }
        }

        // ---- T12: build PV A-fragments fully in-register ----
        // Lane (q=lq,h) holds S^T rows m = (r&3)+8*(r>>2)+4h. Fragment for
        // ks2 needs m-run [16*ks2+8h, +8): lo half from the h'=0 lane's
        // d-pairs, hi half from the h'=1 lane's. One permlane32_swap yields
        // both fragment words (r.x for the lo-m pair, r.y for the hi-m pair).
        f16x8 pfr[4];
        #pragma unroll
        for (int mt2 = 0; mt2 < 2; mt2++) {
            f32x16 sv = mt2 ? s1 : s0;
            u32 d0 = pk2(sv[0], sv[1]),  d1 = pk2(sv[2], sv[3]);
            u32 d2 = pk2(sv[4], sv[5]),  d3 = pk2(sv[6], sv[7]);
            u32 d4 = pk2(sv[8], sv[9]),  d5 = pk2(sv[10], sv[11]);
            u32 d6 = pk2(sv[12], sv[13]), d7 = pk2(sv[14], sv[15]);
            u32x2 p02 = pl32_swap(d0, d2);
            u32x2 p13 = pl32_swap(d1, d3);
            u32x2 p46 = pl32_swap(d4, d6);
            u32x2 p57 = pl32_swap(d5, d7);
            uint4 fa = {p02.x, p13.x, p02.y, p13.y};
            uint4 fb = {p46.x, p57.x, p46.y, p57.y};
            pfr[mt2 * 2 + 0] = __builtin_bit_cast(f16x8, fa);
            pfr[mt2 * 2 + 1] = __builtin_bit_cast(f16x8, fb);
        }

        // PV: D[q][c] += P*V (am), P*(v^2 hi) + P*(v^2 lo) (aq).
        // v^2 hi/lo computed in-register from the V fragment (exact Dekker).
        __builtin_amdgcn_s_setprio(1);
        #pragma unroll
        for (int ks = 0; ks < 4; ks++) {
            f16x8 pf = pfr[ks];
            #pragma unroll
            for (int ct = 0; ct < 2; ct++) {
                f16x8 vf = ldh8(Vs + (ct * 32 + lq) * 72 + ks * 16 + h * 8);
                am[ct] = MFMA32(pf, vf, am[ct]);
                f16x8 vh = vf * vf;                                  // round(v^2)
                f16x8 vl = __builtin_elementwise_fma(vf, vf, -vh);   // exact residual
                aq[ct] = MFMA32(pf, vh, aq[ct]);
                aq[ct] = MFMA32(pf, vl, aq[ct]);
            }
        }
        __builtin_amdgcn_s_setprio(0);
        barrier_nv();
    }

    // ---------------- epilogue: out = std * norm(content) + mean ----------
    float inv = 1.0f / lrow;
    float iv[16];
    #pragma unroll
    for (int r = 0; r < 16; r++) iv[r] = __shfl(inv, (r & 3) + 8 * (r >> 2) + 4 * h);
    float* Ms = (float*)smem;                  // [64 c][132 q] f32
    float* Ss = (float*)(smem + 33792);
    #pragma unroll
    for (int ct = 0; ct < 2; ct++)
        #pragma unroll
        for (int rq = 0; rq < 4; rq++) {
            f32x4 mv, sv;
            #pragma unroll
            for (int j = 0; j < 4; j++) {
                int r = 4 * rq + j;
                float mean = am[ct][r] * iv[r];
                float ex2 = aq[ct][r] * iv[r];
                float var = ex2 - mean * mean;
                mv[j] = mean;
                sv[j] = sqrtf(fmaxf(var, 0.f));
            }
            int c = ct * 32 + lq;
            int qloc = w * 32 + 8 * rq + 4 * h;
            *(f32x4*)(Ms + c * 132 + qloc) = mv;
            *(f32x4*)(Ss + c * 132 + qloc) = sv;
        }
    __syncthreads();
    #pragma unroll
    for (int pass = 0; pass < 8; pass++) {
        int c = pass * 8 + (t >> 5);
        int qloc = (t & 31) * 4;
        f32x4 mv = *(const f32x4*)(Ms + c * 132 + qloc);
        f32x4 sv = *(const f32x4*)(Ss + c * 132 + qloc);
        int gc = coff + c;
        size_t basei = ((size_t)b * 256 + gc) * 4096 + q0 + qloc;
        float4 cv = *(const float4*)(content + basei);
        float cmv = cm[b * 256 + gc], crv = cr[b * 256 + gc];
        float4 o;
        o.x = sv[0] * ((cv.x - cmv) * crv) + mv[0];
        o.y = sv[1] * ((cv.y - cmv) * crv) + mv[1];
        o.z = sv[2] * ((cv.z - cmv) * crv) + mv[2];
        o.w = sv[3] * ((cv.w - cmv) * crv) + mv[3];
        *(float4*)(out + basei) = o;
    }
}

// ---------------------------------------------------------------------------
extern "C" void kernel_launch(void* const* d_in, const int* in_sizes, int n_in,
                              void* d_out, int out_size, void* d_ws, size_t ws_size,
                              hipStream_t stream) {
    const float* content = (const float*)d_in[0];
    const float* style   = (const float*)d_in[1];
    const float* ckey    = (const float*)d_in[2];
    const float* skey    = (const float*)d_in[3];
    const float* Wf      = (const float*)d_in[4];
    const float* bfp     = (const float*)d_in[5];
    const float* Wg      = (const float*)d_in[6];
    const float* bgp     = (const float*)d_in[7];
    const float* Wh      = (const float*)d_in[8];
    const float* bhp     = (const float*)d_in[9];
    float* out = (float*)d_out;
    char* ws = (char*)d_ws;

    float* cm = (float*)(ws + 0);               //  4 KiB
    float* cr = (float*)(ws + 4096);            //  4 KiB
    u16*   Wb = (u16*)(ws + 8192);              //  384 KiB
    u16*   A  = (u16*)(ws + 1048576);           //  8 MiB: Qt
    u16*   Bv = (u16*)(ws + 9437184);           //  8 MiB: Vt [c][tok]
    u16*   Cc = (u16*)(ws + 17825792);          //  8 MiB: Xk -> Kt
    u16*   X1 = (u16*)d_out;                    //  8 MiB scratch (style^T)
    u16*   X2 = (u16*)d_out + 4194304;          //  8 MiB scratch (ckey^T)

    k_stats<<<dim3(1024), 256, 0, stream>>>(content, cm, cr);
    k_prep<<<dim3(64, 4, 15), 256, 0, stream>>>(style, ckey, skey, Wf, Wg, Wh,
                                                X1, X2, Cc, Wb);
    k_gemm<<<dim3(32, 4, 3), 256, 0, stream>>>(X1, X2, Cc, A, Bv, Wb, bfp, bgp, bhp);
    k_flash<<<dim3(32, 4, 4), 256, 0, stream>>>(A, Cc, Bv, content, cm, cr, out);
}

// Round 3
// 500.358 us; speedup vs baseline: 1.0793x; 1.0793x over previous
//
#include <hip/hip_runtime.h>

// ---------------------------------------------------------------------------
// ASA (AdaAttN-style) fused pipeline for MI355X / gfx950
// B=4, C=256, H=W=64 -> N=M=4096 tokens.
//
// R12 (async-LDS rebuild of T14; T12/T13/T5/trees kept from R11 which passed):
//  * K double-buffered (32 KiB x2) + V single-buffered (8 KiB) in LDS, staged
//    with __builtin_amdgcn_global_load_lds (zero data-VGPR cost -- R11's 40
//    persistent prefetch VGPRs caused a 610 MB/dispatch scratch-spill).
//  * Rule-21 swizzle: linear LDS dest, inverse-swizzled global source,
//    byte ^= (row&7)<<4 on reads. Replaces the old +8 u16 row padding.
//  * Per iter: issue V(it), K(it+1) -> QK^T -> softmax/T12/T13 ->
//    vmcnt(8)+barrier (V done; K(it+1) stays in flight) -> PV ->
//    vmcnt(0)+barrier. Load latency never exposed.
//  * T12 in-register P via permlane32_swap; T13 defer-max (THR=8 nats);
//    T5 setprio around MFMA clusters; tree reductions.
//
//  ws + 0      : cm [1024] f32      ws + 4096  : cr [1024] f32
//  ws + 8192   : Wb [3*65536] fp16
//  ws + 1 MiB  : A  8 MiB fp16  Qt
//  ws + 9 MiB  : Bv 8 MiB fp16  Vt [c][tok]
//  ws + 17 MiB : Cc 8 MiB fp16  Xk -> Kt (in-place)
//  d_out lo/hi : X1 (style^T), X2 (ckey^T) scratch
// ---------------------------------------------------------------------------

typedef unsigned int u32;
typedef unsigned short u16;
typedef _Float16 f16x8 __attribute__((ext_vector_type(8)));
typedef float f32x4 __attribute__((ext_vector_type(4)));
typedef float f32x16 __attribute__((ext_vector_type(16)));
typedef unsigned int u32x2 __attribute__((ext_vector_type(2)));
typedef unsigned __attribute__((address_space(3))) as3_u32;
typedef const unsigned __attribute__((address_space(1))) as1_u32;

#define L2E 1.44269504088896340736f
#define MFMA(a, b, c) __builtin_amdgcn_mfma_f32_16x16x32_f16(a, b, c, 0, 0, 0)
#define MFMA32(a, b, c) __builtin_amdgcn_mfma_f32_32x32x16_f16(a, b, c, 0, 0, 0)
#define EXP2(x) __builtin_amdgcn_exp2f(x)

__device__ __forceinline__ u16 h_bits(_Float16 h) { return __builtin_bit_cast(u16, h); }
__device__ __forceinline__ u16 f2h(float f) { return h_bits((_Float16)f); }
__device__ __forceinline__ u32 pk2(float a, float b) {
    return (u32)f2h(a) | ((u32)f2h(b) << 16);
}

__device__ __forceinline__ f16x8 ldh8(const u16* p) {
    uint4 v = *(const uint4*)p;
    return __builtin_bit_cast(f16x8, v);
}

// async 16B/lane global->LDS. lds must be wave-uniform; writes lds + lane*16.
__device__ __forceinline__ void gll16(const u16* g, const void* lds) {
    __builtin_amdgcn_global_load_lds((as1_u32*)g,
                                     (as3_u32*)(unsigned)(unsigned long long)lds,
                                     16, 0, 0);
}

// lane i<32: r.x = a[i],    r.y = a[i+32]
// lane i>=32: r.x = b[i-32], r.y = b[i]
__device__ __forceinline__ u32x2 pl32_swap(u32 a, u32 b) {
#if __has_builtin(__builtin_amdgcn_permlane32_swap)
    return __builtin_amdgcn_permlane32_swap(a, b, false, false);
#else
    asm("v_permlane32_swap_b32 %0, %1" : "+v"(a), "+v"(b));
    u32x2 r; r.x = a; r.y = b; return r;
#endif
}

// ---------------- content stats: mean & rstd per (b,c) ---------------------
__global__ void k_stats(const float* __restrict__ content,
                        float* __restrict__ cm, float* __restrict__ cr) {
    int blk = blockIdx.x;                       // 0..1023 = b*256+c
    const float* p = content + (size_t)blk * 4096;
    int t = threadIdx.x;
    float s = 0.f, ss = 0.f;
    for (int i = 0; i < 4; i++) {
        float4 v = *(const float4*)(p + (i * 256 + t) * 4);
        s  += (v.x + v.y) + (v.z + v.w);
        ss += (v.x * v.x + v.y * v.y) + (v.z * v.z + v.w * v.w);
    }
    for (int d = 32; d >= 1; d >>= 1) { s += __shfl_xor(s, d); ss += __shfl_xor(ss, d); }
    __shared__ __align__(16) float as[4], ass[4];
    int w = t >> 6;
    if ((t & 63) == 0) { as[w] = s; ass[w] = ss; }
    __syncthreads();
    if (t == 0) {
        s  = (as[0] + as[1]) + (as[2] + as[3]);
        ss = (ass[0] + ass[1]) + (ass[2] + ass[3]);
        float mean = s * (1.0f / 4096.0f);
        float var = (ss - s * mean) * (1.0f / 4095.0f);   // unbiased (ddof=1)
        cm[blk] = mean;
        cr[blk] = rsqrtf(var + 1e-5f);
    }
}

// ---------------- prep: 3 transposes + weight cvt in ONE launch ------------
// z 0..3: style->X1 ; 4..7: ckey->X2 ; 8..11: skey->Cc ; 12..14: weights
__global__ void k_prep(const float* __restrict__ style, const float* __restrict__ ckey,
                       const float* __restrict__ skey,
                       const float* __restrict__ Wf, const float* __restrict__ Wg,
                       const float* __restrict__ Wh,
                       u16* __restrict__ X1, u16* __restrict__ X2, u16* __restrict__ Cc,
                       u16* __restrict__ Wb) {
    int z = blockIdx.z, t = threadIdx.x;
    if (z >= 12) {
        if (blockIdx.y != 0) return;
        int m = z - 12;
        const float* src = (m == 0) ? Wf : ((m == 1) ? Wg : Wh);
        u16* dst = Wb + m * 65536;
        int i = (blockIdx.x * 256 + t) * 4;
        float4 v = *(const float4*)(src + i);
        ushort4 o;
        o.x = f2h(v.x); o.y = f2h(v.y); o.z = f2h(v.z); o.w = f2h(v.w);
        *(ushort4*)(dst + i) = o;
        return;
    }
    int tensor = z >> 2, b = z & 3;
    const float* src = ((tensor == 0) ? style : ((tensor == 1) ? ckey : skey))
                       + (size_t)b * 256 * 4096;
    u16* dst = ((tensor == 0) ? X1 : ((tensor == 1) ? X2 : Cc)) + (size_t)b * 4096 * 256;
    int c0 = blockIdx.y * 64, t0 = blockIdx.x * 64;
    __shared__ __align__(16) float ls[64][65];
    int tr = t >> 4, tc = t & 15;
    for (int i = 0; i < 4; i++) {
        int c_off = i * 16 + tr;
        float4 v = *(const float4*)(src + (size_t)(c0 + c_off) * 4096 + t0 + tc * 4);
        ls[tc * 4 + 0][c_off] = v.x;
        ls[tc * 4 + 1][c_off] = v.y;
        ls[tc * 4 + 2][c_off] = v.z;
        ls[tc * 4 + 3][c_off] = v.w;
    }
    __syncthreads();
    for (int i = 0; i < 4; i++) {
        int tokrow = i * 16 + tr;
        ushort4 o;
        o.x = f2h(ls[tokrow][tc * 4 + 0]);
        o.y = f2h(ls[tokrow][tc * 4 + 1]);
        o.z = f2h(ls[tokrow][tc * 4 + 2]);
        o.w = f2h(ls[tokrow][tc * 4 + 3]);
        *(ushort4*)(dst + (size_t)(t0 + tokrow) * 256 + c0 + tc * 4) = o;
    }
}

// ---------------- all three conv1x1 GEMMs, one launch -----------------------
// mode 0: Q = X2*Wf^T + bf -> A (token-major)
// mode 1: K = Cc*Wg^T + bg -> Cc (in-place, token-major)
// mode 2: V = Wh*X1 + bh   -> Bv (channel-major)
__launch_bounds__(256, 2)
__global__ void k_gemm(const u16* X1, const u16* X2, u16* Cc,
                       u16* A, u16* Bv, const u16* __restrict__ Wb,
                       const float* __restrict__ bfp, const float* __restrict__ bgp,
                       const float* __restrict__ bhp) {
    int mode = blockIdx.z, b = blockIdx.y, tok0 = blockIdx.x * 128;
    const u16* X = ((mode == 0) ? X2 : ((mode == 1) ? (const u16*)Cc : X1))
                   + (size_t)b * 4096 * 256;
    const u16* W = Wb + mode * 65536;
    const float* bias = (mode == 0) ? bfp : ((mode == 1) ? bgp : bhp);
    __shared__ __align__(16) u16 wt[256 * 40];
    int t = threadIdx.x, w = t >> 6, lane = t & 63, ln = lane & 15, quad = lane >> 4;

    f32x4 acc[8][4];
    for (int i = 0; i < 8; i++)
        for (int j = 0; j < 4; j++) acc[i][j] = f32x4{0.f, 0.f, 0.f, 0.f};

    for (int ks = 0; ks < 8; ks++) {
        {   // stage W[o = t][ks*32 .. +32) -> LDS : full 64 B per row
            const u16* wr = W + t * 256 + ks * 32;
            uint4 w0 = *(const uint4*)(wr + 0);
            uint4 w1 = *(const uint4*)(wr + 8);
            uint4 w2 = *(const uint4*)(wr + 16);
            uint4 w3 = *(const uint4*)(wr + 24);
            *(uint4*)(wt + t * 40 + 0)  = w0;
            *(uint4*)(wt + t * 40 + 8)  = w1;
            *(uint4*)(wt + t * 40 + 16) = w2;
            *(uint4*)(wt + t * 40 + 24) = w3;
        }
        __syncthreads();
        f16x8 wf[4];
        #pragma unroll
        for (int ct = 0; ct < 4; ct++)
            wf[ct] = ldh8(wt + (w * 64 + ct * 16 + ln) * 40 + quad * 8);
        #pragma unroll
        for (int rt = 0; rt < 8; rt++) {
            f16x8 xf = ldh8(X + (size_t)(tok0 + rt * 16 + ln) * 256 + ks * 32 + quad * 8);
            if (mode < 2) {
                #pragma unroll
                for (int ct = 0; ct < 4; ct++) acc[rt][ct] = MFMA(xf, wf[ct], acc[rt][ct]);
            } else {
                #pragma unroll
                for (int ct = 0; ct < 4; ct++) acc[rt][ct] = MFMA(wf[ct], xf, acc[rt][ct]);
            }
        }
        __syncthreads();
    }

    if (mode < 2) {
        u16* O = ((mode == 0) ? A : Cc) + (size_t)b * 4096 * 256;
        float bv[4];
        #pragma unroll
        for (int ct = 0; ct < 4; ct++) bv[ct] = bias[w * 64 + ct * 16 + ln];
        #pragma unroll
        for (int rt = 0; rt < 8; rt++)
            #pragma unroll
            for (int ct = 0; ct < 4; ct++)
                #pragma unroll
                for (int r = 0; r < 4; r++) {
                    int tok = tok0 + rt * 16 + quad * 4 + r;
                    int o = w * 64 + ct * 16 + ln;
                    O[(size_t)tok * 256 + o] = f2h(acc[rt][ct][r] + bv[ct]);
                }
    } else {
        u16* OV = Bv + (size_t)b * 256 * 4096;
        #pragma unroll
        for (int ct = 0; ct < 4; ct++)
            #pragma unroll
            for (int r = 0; r < 4; r++) {
                int o = w * 64 + ct * 16 + quad * 4 + r;
                float bb = bias[o];
                #pragma unroll
                for (int rt = 0; rt < 8; rt++) {
                    int tok = tok0 + rt * 16 + ln;
                    OV[(size_t)o * 4096 + tok] = f2h(acc[rt][ct][r] + bb);
                }
            }
    }
}

// ---------------- flash attention + fused AdaIN epilogue -------------------
// grid: (32 q-tiles of 128, 4 batch, 4 c-quarters) = 512 blocks = 2/CU.
// LDS: K[2][64][256] u16 swizzled (0, 32768B) | V[64][64] u16 swizzled (65536B)
__launch_bounds__(256)
__global__ void k_flash(const u16* __restrict__ Qt, const u16* __restrict__ Kt,
                        const u16* __restrict__ Vt,
                        const float* __restrict__ content, const float* __restrict__ cm,
                        const float* __restrict__ cr, float* __restrict__ out) {
    __shared__ __align__(16) char smem[73728];
    const u16* KsU = (const u16*)smem;
    int t = threadIdx.x, w = t >> 6, l = t & 63, lq = l & 31, h = l >> 5;

    int b = blockIdx.y, q0 = blockIdx.x * 128, coff = blockIdx.z * 64;

    const u16* Kg = Kt + (size_t)b * 4096 * 256;
    const u16* Vg = Vt + ((size_t)b * 256 + coff) * 4096;

    // ---- staging geometry (rule-21: linear LDS dest, inv-swizzled source) --
    // K tile row = 512 B; LDS slot p -> row p>>9, stored col = (p&511)^((row&7)<<4)
    const u16* ksrc;
    {
        int qb = w * 1024 + l * 16;                 // byte slot in 4096-chunk
        int r0 = qb >> 9;                           // 0..7
        int swz = (qb & 511) ^ ((r0 & 7) << 4);
        ksrc = Kg + r0 * 256 + (swz >> 1);          // + (m0 + i*8)*256
    }
    // V tile row = 128 B; slot p -> row p>>7, col = (p&127)^((row&7)<<4)
    const u16* vsrc;
    {
        int rv = w * 8 + (l >> 3);                  // 0..31 (+32 for i=1)
        int swz = ((l & 7) << 4) ^ ((rv & 7) << 4);
        vsrc = Vg + (size_t)rv * 4096 + (swz >> 1); // + i*32*4096 + m0
    }
    const char* ldsKw = smem + w * 1024;            // + koffB + i*4096
    const char* ldsVw = smem + 65536 + w * 1024;    // + i*4096

    // ---- read-side swizzle: addr_u16 = row*stride + ((ks<<4) ^ uu) ---------
    int uu = (h ^ (lq & 7)) << 3;                   // u16 units
    int tab0 = uu, tab1 = 16 ^ uu, tab2 = 32 ^ uu, tab3 = 48 ^ uu;
    int kb0 = lq * 256;                             // K row base (u16)
    int vb0 = 32768 + lq * 64;                      // V base (u16, +VOFF)

    // Q as B-operand fragments, pinned: col q = lq, k = h*8+j (+16ks)
    f16x8 qf[16];
    {
        const u16* qp = Qt + ((size_t)b * 4096 + q0 + w * 32 + lq) * 256 + h * 8;
        #pragma unroll
        for (int ks = 0; ks < 16; ks++) qf[ks] = ldh8(qp + ks * 16);
    }

    f32x16 am[2], aq[2];
    #pragma unroll
    for (int i = 0; i < 16; i++) { am[0][i] = 0.f; am[1][i] = 0.f; aq[0][i] = 0.f; aq[1][i] = 0.f; }
    float mrow = -1e30f, lrow = 0.f;

    // ---- prologue: stage K(0) into buffer 0 -------------------------------
    #pragma unroll
    for (int i = 0; i < 8; i++) gll16(ksrc + i * 2048, ldsKw + i * 4096);
    asm volatile("s_waitcnt vmcnt(0)" ::: "memory");
    __builtin_amdgcn_s_barrier();

    int koffB = 0;                                  // current K buffer (bytes)
    for (int it = 0; it < 64; it++) {
        // issue V(it) (2 loads), then K(it+1) (8 loads) -- stay in flight
        {
            int m0 = it * 64;
            #pragma unroll
            for (int i = 0; i < 2; i++)
                gll16(vsrc + (size_t)i * 131072 + m0, ldsVw + i * 4096);
        }
        if (it < 63) {
            int m0n = (it + 1) * 64 * 256;
            #pragma unroll
            for (int i = 0; i < 8; i++)
                gll16(ksrc + m0n + i * 2048, ldsKw + (koffB ^ 32768) + i * 4096);
        }

        // S^T[m][q] = K * Q^T   (two 32-row m-tiles) from current K buffer
        int kb = (koffB >> 1) + kb0;
        f32x16 s0, s1;
        #pragma unroll
        for (int i = 0; i < 16; i++) { s0[i] = 0.f; s1[i] = 0.f; }
        __builtin_amdgcn_s_setprio(1);
        #pragma unroll
        for (int ks = 0; ks < 16; ks++) {
            int off = ((ks & 3) == 0 ? tab0 : (ks & 3) == 1 ? tab1
                      : (ks & 3) == 2 ? tab2 : tab3) + (ks >> 2) * 64;
            f16x8 k0 = ldh8(KsU + kb + off);
            s0 = MFMA32(k0, qf[ks], s0);
            f16x8 k1 = ldh8(KsU + kb + 8192 + off);
            s1 = MFMA32(k1, qf[ks], s1);
        }
        __builtin_amdgcn_s_setprio(0);

        // online softmax over m: tree max (depth 5) + one shfl_xor(32)
        float m8[8];
        #pragma unroll
        for (int r = 0; r < 8; r++)
            m8[r] = fmaxf(fmaxf(s0[r], s0[r + 8]), fmaxf(s1[r], s1[r + 8]));
        #pragma unroll
        for (int d = 4; d >= 1; d >>= 1)
            #pragma unroll
            for (int r = 0; r < d; r++) m8[r] = fmaxf(m8[r], m8[r + d]);
        float mt = fmaxf(m8[0], __shfl_xor(m8[0], 32));

        // T13 defer-max: only rescale when some row grew by > 8 nats.
        float mn, al;
        bool resc = !__all(mt - mrow <= 8.0f);
        if (resc) {
            mn = fmaxf(mrow, mt);
            al = EXP2((mrow - mn) * L2E);
            mrow = mn;
        } else {
            mn = mrow;
            al = 1.0f;
        }
        float base = mn * L2E;
        #pragma unroll
        for (int r = 0; r < 16; r++) {
            float p0 = (float)(_Float16)EXP2(__builtin_fmaf(s0[r], L2E, -base));
            float p1 = (float)(_Float16)EXP2(__builtin_fmaf(s1[r], L2E, -base));
            s0[r] = p0; s1[r] = p1;
        }
        float a8[8];
        #pragma unroll
        for (int r = 0; r < 8; r++)
            a8[r] = (s0[r] + s0[r + 8]) + (s1[r] + s1[r + 8]);
        #pragma unroll
        for (int d = 4; d >= 1; d >>= 1)
            #pragma unroll
            for (int r = 0; r < d; r++) a8[r] += a8[r + d];
        float rs = a8[0] + __shfl_xor(a8[0], 32);
        lrow = lrow * al + rs;

        if (resc) {
            #pragma unroll
            for (int r = 0; r < 16; r++) {
                float sc = __shfl(al, 8 * (r >> 2) + 4 * h + (r & 3));
                am[0][r] *= sc; am[1][r] *= sc;
                aq[0][r] *= sc; aq[1][r] *= sc;
            }
        }

        // ---- T12: build PV A-fragments fully in-register ----
        f16x8 pfr[4];
        #pragma unroll
        for (int mt2 = 0; mt2 < 2; mt2++) {
            f32x16 sv = mt2 ? s1 : s0;
            u32 d0 = pk2(sv[0], sv[1]),  d1 = pk2(sv[2], sv[3]);
            u32 d2 = pk2(sv[4], sv[5]),  d3 = pk2(sv[6], sv[7]);
            u32 d4 = pk2(sv[8], sv[9]),  d5 = pk2(sv[10], sv[11]);
            u32 d6 = pk2(sv[12], sv[13]), d7 = pk2(sv[14], sv[15]);
            u32x2 p02 = pl32_swap(d0, d2);
            u32x2 p13 = pl32_swap(d1, d3);
            u32x2 p46 = pl32_swap(d4, d6);
            u32x2 p57 = pl32_swap(d5, d7);
            uint4 fa = {p02.x, p13.x, p02.y, p13.y};
            uint4 fb = {p46.x, p57.x, p46.y, p57.y};
            pfr[mt2 * 2 + 0] = __builtin_bit_cast(f16x8, fa);
            pfr[mt2 * 2 + 1] = __builtin_bit_cast(f16x8, fb);
        }

        // mid wait: V(it) landed (oldest 2 of 10); K(it+1) stays in flight.
        if (it < 63) asm volatile("s_waitcnt vmcnt(8)" ::: "memory");
        else         asm volatile("s_waitcnt vmcnt(0)" ::: "memory");
        __builtin_amdgcn_s_barrier();

        // PV: D[q][c] += P*V (am), P*(v^2 hi) + P*(v^2 lo) (aq).
        __builtin_amdgcn_s_setprio(1);
        #pragma unroll
        for (int ks = 0; ks < 4; ks++) {
            f16x8 pf = pfr[ks];
            int tv = (ks == 0 ? tab0 : ks == 1 ? tab1 : ks == 2 ? tab2 : tab3);
            #pragma unroll
            for (int ct = 0; ct < 2; ct++) {
                f16x8 vf = ldh8(KsU + vb0 + ct * 2048 + tv);
                am[ct] = MFMA32(pf, vf, am[ct]);
                f16x8 vh = vf * vf;                                  // round(v^2)
                f16x8 vl = __builtin_elementwise_fma(vf, vf, -vh);   // exact residual
                aq[ct] = MFMA32(pf, vh, aq[ct]);
                aq[ct] = MFMA32(pf, vl, aq[ct]);
            }
        }
        __builtin_amdgcn_s_setprio(0);

        // end: drain K(it+1) writes (issued a full phase ago) + sync
        asm volatile("s_waitcnt vmcnt(0)" ::: "memory");
        __builtin_amdgcn_s_barrier();
        koffB ^= 32768;
    }

    // ---------------- epilogue: out = std * norm(content) + mean ----------
    float inv = 1.0f / lrow;
    float iv[16];
    #pragma unroll
    for (int r = 0; r < 16; r++) iv[r] = __shfl(inv, (r & 3) + 8 * (r >> 2) + 4 * h);
    float* Ms = (float*)smem;                  // [64 c][132 q] f32
    float* Ss = (float*)(smem + 33792);
    #pragma unroll
    for (int ct = 0; ct < 2; ct++)
        #pragma unroll
        for (int rq = 0; rq < 4; rq++) {
            f32x4 mv, sv;
            #pragma unroll
            for (int j = 0; j < 4; j++) {
                int r = 4 * rq + j;
                float mean = am[ct][r] * iv[r];
                float ex2 = aq[ct][r] * iv[r];
                float var = ex2 - mean * mean;
                mv[j] = mean;
                sv[j] = sqrtf(fmaxf(var, 0.f));
            }
            int c = ct * 32 + lq;
            int qloc = w * 32 + 8 * rq + 4 * h;
            *(f32x4*)(Ms + c * 132 + qloc) = mv;
            *(f32x4*)(Ss + c * 132 + qloc) = sv;
        }
    __syncthreads();
    #pragma unroll
    for (int pass = 0; pass < 8; pass++) {
        int c = pass * 8 + (t >> 5);
        int qloc = (t & 31) * 4;
        f32x4 mv = *(const f32x4*)(Ms + c * 132 + qloc);
        f32x4 sv = *(const f32x4*)(Ss + c * 132 + qloc);
        int gc = coff + c;
        size_t basei = ((size_t)b * 256 + gc) * 4096 + q0 + qloc;
        float4 cv = *(const float4*)(content + basei);
        float cmv = cm[b * 256 + gc], crv = cr[b * 256 + gc];
        float4 o;
        o.x = sv[0] * ((cv.x - cmv) * crv) + mv[0];
        o.y = sv[1] * ((cv.y - cmv) * crv) + mv[1];
        o.z = sv[2] * ((cv.z - cmv) * crv) + mv[2];
        o.w = sv[3] * ((cv.w - cmv) * crv) + mv[3];
        *(float4*)(out + basei) = o;
    }
}

// ---------------------------------------------------------------------------
extern "C" void kernel_launch(void* const* d_in, const int* in_sizes, int n_in,
                              void* d_out, int out_size, void* d_ws, size_t ws_size,
                              hipStream_t stream) {
    const float* content = (const float*)d_in[0];
    const float* style   = (const float*)d_in[1];
    const float* ckey    = (const float*)d_in[2];
    const float* skey    = (const float*)d_in[3];
    const float* Wf      = (const float*)d_in[4];
    const float* bfp     = (const float*)d_in[5];
    const float* Wg      = (const float*)d_in[6];
    const float* bgp     = (const float*)d_in[7];
    const float* Wh      = (const float*)d_in[8];
    const float* bhp     = (const float*)d_in[9];
    float* out = (float*)d_out;
    char* ws = (char*)d_ws;

    float* cm = (float*)(ws + 0);               //  4 KiB
    float* cr = (float*)(ws + 4096);            //  4 KiB
    u16*   Wb = (u16*)(ws + 8192);              //  384 KiB
    u16*   A  = (u16*)(ws + 1048576);           //  8 MiB: Qt
    u16*   Bv = (u16*)(ws + 9437184);           //  8 MiB: Vt [c][tok]
    u16*   Cc = (u16*)(ws + 17825792);          //  8 MiB: Xk -> Kt
    u16*   X1 = (u16*)d_out;                    //  8 MiB scratch (style^T)
    u16*   X2 = (u16*)d_out + 4194304;          //  8 MiB scratch (ckey^T)

    k_stats<<<dim3(1024), 256, 0, stream>>>(content, cm, cr);
    k_prep<<<dim3(64, 4, 15), 256, 0, stream>>>(style, ckey, skey, Wf, Wg, Wh,
                                                X1, X2, Cc, Wb);
    k_gemm<<<dim3(32, 4, 3), 256, 0, stream>>>(X1, X2, Cc, A, Bv, Wb, bfp, bgp, bhp);
    k_flash<<<dim3(32, 4, 4), 256, 0, stream>>>(A, Cc, Bv, content, cm, cr, out);
}

// Round 4
// 406.833 us; speedup vs baseline: 1.3274x; 1.2299x over previous
//
#include <hip/hip_runtime.h>

// ---------------------------------------------------------------------------
// ASA (AdaAttN-style) fused pipeline for MI355X / gfx950
// B=4, C=256, H=W=64 -> N=M=4096 tokens.
//
// R13 (fix R12's two regressions):
//  * LDS back to 67584 B (R9's proven 2-blocks/CU size): V is no longer
//    staged in LDS at all. PV reads V fragments (16 B contiguous) straight
//    from global -- the 512 KB V slice per (b,cq) is shared by 32 blocks and
//    L2-resident. Kills the 8-way-conflicted V ds_reads (R12: 21M conflicts)
//    and the mid-phase barrier.
//  * K double-buffered via global_load_lds (zero data-VGPR staging),
//    rule-21 swizzle; K reads measured conflict-free in R12.
//  * ONE vmcnt(0)+s_barrier per iteration; K(it+1) issued a full phase
//    before its drain -> no exposed load latency.
//  * amdgpu_waves_per_eu(2,2): 256-VGPR budget, no R11-style spill.
//  * T12 in-register P via permlane32_swap; T13 defer-max (THR=8 nats);
//    T5 setprio around MFMA clusters; tree reductions.
//
//  ws + 0      : cm [1024] f32      ws + 4096  : cr [1024] f32
//  ws + 8192   : Wb [3*65536] fp16
//  ws + 1 MiB  : A  8 MiB fp16  Qt
//  ws + 9 MiB  : Bv 8 MiB fp16  Vt [c][tok]
//  ws + 17 MiB : Cc 8 MiB fp16  Xk -> Kt (in-place)
//  d_out lo/hi : X1 (style^T), X2 (ckey^T) scratch
// ---------------------------------------------------------------------------

typedef unsigned int u32;
typedef unsigned short u16;
typedef _Float16 f16x8 __attribute__((ext_vector_type(8)));
typedef float f32x4 __attribute__((ext_vector_type(4)));
typedef float f32x16 __attribute__((ext_vector_type(16)));
typedef unsigned int u32x2 __attribute__((ext_vector_type(2)));
typedef unsigned __attribute__((address_space(3))) as3_u32;
typedef const unsigned __attribute__((address_space(1))) as1_u32;

#define L2E 1.44269504088896340736f
#define MFMA(a, b, c) __builtin_amdgcn_mfma_f32_16x16x32_f16(a, b, c, 0, 0, 0)
#define MFMA32(a, b, c) __builtin_amdgcn_mfma_f32_32x32x16_f16(a, b, c, 0, 0, 0)
#define EXP2(x) __builtin_amdgcn_exp2f(x)

__device__ __forceinline__ u16 h_bits(_Float16 h) { return __builtin_bit_cast(u16, h); }
__device__ __forceinline__ u16 f2h(float f) { return h_bits((_Float16)f); }
__device__ __forceinline__ u32 pk2(float a, float b) {
    return (u32)f2h(a) | ((u32)f2h(b) << 16);
}

__device__ __forceinline__ f16x8 ldh8(const u16* p) {
    uint4 v = *(const uint4*)p;
    return __builtin_bit_cast(f16x8, v);
}

// async 16B/lane global->LDS. lds must be wave-uniform; writes lds + lane*16.
__device__ __forceinline__ void gll16(const u16* g, const void* lds) {
    __builtin_amdgcn_global_load_lds((as1_u32*)g,
                                     (as3_u32*)(unsigned)(unsigned long long)lds,
                                     16, 0, 0);
}

// lane i<32: r.x = a[i],    r.y = a[i+32]
// lane i>=32: r.x = b[i-32], r.y = b[i]
__device__ __forceinline__ u32x2 pl32_swap(u32 a, u32 b) {
#if __has_builtin(__builtin_amdgcn_permlane32_swap)
    return __builtin_amdgcn_permlane32_swap(a, b, false, false);
#else
    asm("v_permlane32_swap_b32 %0, %1" : "+v"(a), "+v"(b));
    u32x2 r; r.x = a; r.y = b; return r;
#endif
}

// ---------------- content stats: mean & rstd per (b,c) ---------------------
__global__ void k_stats(const float* __restrict__ content,
                        float* __restrict__ cm, float* __restrict__ cr) {
    int blk = blockIdx.x;                       // 0..1023 = b*256+c
    const float* p = content + (size_t)blk * 4096;
    int t = threadIdx.x;
    float s = 0.f, ss = 0.f;
    for (int i = 0; i < 4; i++) {
        float4 v = *(const float4*)(p + (i * 256 + t) * 4);
        s  += (v.x + v.y) + (v.z + v.w);
        ss += (v.x * v.x + v.y * v.y) + (v.z * v.z + v.w * v.w);
    }
    for (int d = 32; d >= 1; d >>= 1) { s += __shfl_xor(s, d); ss += __shfl_xor(ss, d); }
    __shared__ __align__(16) float as[4], ass[4];
    int w = t >> 6;
    if ((t & 63) == 0) { as[w] = s; ass[w] = ss; }
    __syncthreads();
    if (t == 0) {
        s  = (as[0] + as[1]) + (as[2] + as[3]);
        ss = (ass[0] + ass[1]) + (ass[2] + ass[3]);
        float mean = s * (1.0f / 4096.0f);
        float var = (ss - s * mean) * (1.0f / 4095.0f);   // unbiased (ddof=1)
        cm[blk] = mean;
        cr[blk] = rsqrtf(var + 1e-5f);
    }
}

// ---------------- prep: 3 transposes + weight cvt in ONE launch ------------
// z 0..3: style->X1 ; 4..7: ckey->X2 ; 8..11: skey->Cc ; 12..14: weights
__global__ void k_prep(const float* __restrict__ style, const float* __restrict__ ckey,
                       const float* __restrict__ skey,
                       const float* __restrict__ Wf, const float* __restrict__ Wg,
                       const float* __restrict__ Wh,
                       u16* __restrict__ X1, u16* __restrict__ X2, u16* __restrict__ Cc,
                       u16* __restrict__ Wb) {
    int z = blockIdx.z, t = threadIdx.x;
    if (z >= 12) {
        if (blockIdx.y != 0) return;
        int m = z - 12;
        const float* src = (m == 0) ? Wf : ((m == 1) ? Wg : Wh);
        u16* dst = Wb + m * 65536;
        int i = (blockIdx.x * 256 + t) * 4;
        float4 v = *(const float4*)(src + i);
        ushort4 o;
        o.x = f2h(v.x); o.y = f2h(v.y); o.z = f2h(v.z); o.w = f2h(v.w);
        *(ushort4*)(dst + i) = o;
        return;
    }
    int tensor = z >> 2, b = z & 3;
    const float* src = ((tensor == 0) ? style : ((tensor == 1) ? ckey : skey))
                       + (size_t)b * 256 * 4096;
    u16* dst = ((tensor == 0) ? X1 : ((tensor == 1) ? X2 : Cc)) + (size_t)b * 4096 * 256;
    int c0 = blockIdx.y * 64, t0 = blockIdx.x * 64;
    __shared__ __align__(16) float ls[64][65];
    int tr = t >> 4, tc = t & 15;
    for (int i = 0; i < 4; i++) {
        int c_off = i * 16 + tr;
        float4 v = *(const float4*)(src + (size_t)(c0 + c_off) * 4096 + t0 + tc * 4);
        ls[tc * 4 + 0][c_off] = v.x;
        ls[tc * 4 + 1][c_off] = v.y;
        ls[tc * 4 + 2][c_off] = v.z;
        ls[tc * 4 + 3][c_off] = v.w;
    }
    __syncthreads();
    for (int i = 0; i < 4; i++) {
        int tokrow = i * 16 + tr;
        ushort4 o;
        o.x = f2h(ls[tokrow][tc * 4 + 0]);
        o.y = f2h(ls[tokrow][tc * 4 + 1]);
        o.z = f2h(ls[tokrow][tc * 4 + 2]);
        o.w = f2h(ls[tokrow][tc * 4 + 3]);
        *(ushort4*)(dst + (size_t)(t0 + tokrow) * 256 + c0 + tc * 4) = o;
    }
}

// ---------------- all three conv1x1 GEMMs, one launch -----------------------
// mode 0: Q = X2*Wf^T + bf -> A (token-major)
// mode 1: K = Cc*Wg^T + bg -> Cc (in-place, token-major)
// mode 2: V = Wh*X1 + bh   -> Bv (channel-major)
__launch_bounds__(256, 2)
__global__ void k_gemm(const u16* X1, const u16* X2, u16* Cc,
                       u16* A, u16* Bv, const u16* __restrict__ Wb,
                       const float* __restrict__ bfp, const float* __restrict__ bgp,
                       const float* __restrict__ bhp) {
    int mode = blockIdx.z, b = blockIdx.y, tok0 = blockIdx.x * 128;
    const u16* X = ((mode == 0) ? X2 : ((mode == 1) ? (const u16*)Cc : X1))
                   + (size_t)b * 4096 * 256;
    const u16* W = Wb + mode * 65536;
    const float* bias = (mode == 0) ? bfp : ((mode == 1) ? bgp : bhp);
    __shared__ __align__(16) u16 wt[256 * 40];
    int t = threadIdx.x, w = t >> 6, lane = t & 63, ln = lane & 15, quad = lane >> 4;

    f32x4 acc[8][4];
    for (int i = 0; i < 8; i++)
        for (int j = 0; j < 4; j++) acc[i][j] = f32x4{0.f, 0.f, 0.f, 0.f};

    for (int ks = 0; ks < 8; ks++) {
        {   // stage W[o = t][ks*32 .. +32) -> LDS : full 64 B per row
            const u16* wr = W + t * 256 + ks * 32;
            uint4 w0 = *(const uint4*)(wr + 0);
            uint4 w1 = *(const uint4*)(wr + 8);
            uint4 w2 = *(const uint4*)(wr + 16);
            uint4 w3 = *(const uint4*)(wr + 24);
            *(uint4*)(wt + t * 40 + 0)  = w0;
            *(uint4*)(wt + t * 40 + 8)  = w1;
            *(uint4*)(wt + t * 40 + 16) = w2;
            *(uint4*)(wt + t * 40 + 24) = w3;
        }
        __syncthreads();
        f16x8 wf[4];
        #pragma unroll
        for (int ct = 0; ct < 4; ct++)
            wf[ct] = ldh8(wt + (w * 64 + ct * 16 + ln) * 40 + quad * 8);
        #pragma unroll
        for (int rt = 0; rt < 8; rt++) {
            f16x8 xf = ldh8(X + (size_t)(tok0 + rt * 16 + ln) * 256 + ks * 32 + quad * 8);
            if (mode < 2) {
                #pragma unroll
                for (int ct = 0; ct < 4; ct++) acc[rt][ct] = MFMA(xf, wf[ct], acc[rt][ct]);
            } else {
                #pragma unroll
                for (int ct = 0; ct < 4; ct++) acc[rt][ct] = MFMA(wf[ct], xf, acc[rt][ct]);
            }
        }
        __syncthreads();
    }

    if (mode < 2) {
        u16* O = ((mode == 0) ? A : Cc) + (size_t)b * 4096 * 256;
        float bv[4];
        #pragma unroll
        for (int ct = 0; ct < 4; ct++) bv[ct] = bias[w * 64 + ct * 16 + ln];
        #pragma unroll
        for (int rt = 0; rt < 8; rt++)
            #pragma unroll
            for (int ct = 0; ct < 4; ct++)
                #pragma unroll
                for (int r = 0; r < 4; r++) {
                    int tok = tok0 + rt * 16 + quad * 4 + r;
                    int o = w * 64 + ct * 16 + ln;
                    O[(size_t)tok * 256 + o] = f2h(acc[rt][ct][r] + bv[ct]);
                }
    } else {
        u16* OV = Bv + (size_t)b * 256 * 4096;
        #pragma unroll
        for (int ct = 0; ct < 4; ct++)
            #pragma unroll
            for (int r = 0; r < 4; r++) {
                int o = w * 64 + ct * 16 + quad * 4 + r;
                float bb = bias[o];
                #pragma unroll
                for (int rt = 0; rt < 8; rt++) {
                    int tok = tok0 + rt * 16 + ln;
                    OV[(size_t)o * 4096 + tok] = f2h(acc[rt][ct][r] + bb);
                }
            }
    }
}

// ---------------- flash attention + fused AdaIN epilogue -------------------
// grid: (32 q-tiles of 128, 4 batch, 4 c-quarters) = 512 blocks = 2/CU.
// LDS: K[2][64][256] u16 swizzled (0, 32768B); epilogue reuses all 67584 B.
// V fragments read directly from global (L2-resident slice).
__launch_bounds__(256)
__attribute__((amdgpu_waves_per_eu(2, 2)))
__global__ void k_flash(const u16* __restrict__ Qt, const u16* __restrict__ Kt,
                        const u16* __restrict__ Vt,
                        const float* __restrict__ content, const float* __restrict__ cm,
                        const float* __restrict__ cr, float* __restrict__ out) {
    __shared__ __align__(16) char smem[67584];
    const u16* KsU = (const u16*)smem;
    int t = threadIdx.x, w = t >> 6, l = t & 63, lq = l & 31, h = l >> 5;

    int b = blockIdx.y, q0 = blockIdx.x * 128, coff = blockIdx.z * 64;

    const u16* Kg = Kt + (size_t)b * 4096 * 256;
    const u16* Vg = Vt + ((size_t)b * 256 + coff) * 4096;

    // ---- K staging geometry (rule-21: linear LDS dest, inv-swizzled src) --
    // K tile row = 512 B; LDS slot p -> row p>>9, stored col = (p&511)^((row&7)<<4)
    const u16* ksrc;
    {
        int qb = w * 1024 + l * 16;                 // byte slot in 4096-chunk
        int r0 = qb >> 9;                           // 0..7
        int swz = (qb & 511) ^ ((r0 & 7) << 4);
        ksrc = Kg + r0 * 256 + (swz >> 1);          // + (m0 + i*8)*256
    }
    const char* ldsKw = smem + w * 1024;            // + koffB + i*4096

    // ---- K read-side swizzle: addr_u16 = row*256 + ((ks<<4) ^ uu) ----------
    int uu = (h ^ (lq & 7)) << 3;                   // u16 units
    int tab0 = uu, tab1 = 16 ^ uu, tab2 = 32 ^ uu, tab3 = 48 ^ uu;
    int kb0 = lq * 256;                             // K row base (u16)

    // Q as B-operand fragments, pinned: col q = lq, k = h*8+j (+16ks)
    f16x8 qf[16];
    {
        const u16* qp = Qt + ((size_t)b * 4096 + q0 + w * 32 + lq) * 256 + h * 8;
        #pragma unroll
        for (int ks = 0; ks < 16; ks++) qf[ks] = ldh8(qp + ks * 16);
    }

    f32x16 am[2], aq[2];
    #pragma unroll
    for (int i = 0; i < 16; i++) { am[0][i] = 0.f; am[1][i] = 0.f; aq[0][i] = 0.f; aq[1][i] = 0.f; }
    float mrow = -1e30f, lrow = 0.f;

    // ---- prologue: stage K(0) into buffer 0 -------------------------------
    #pragma unroll
    for (int i = 0; i < 8; i++) gll16(ksrc + i * 2048, ldsKw + i * 4096);
    asm volatile("s_waitcnt vmcnt(0)" ::: "memory");
    __builtin_amdgcn_s_barrier();

    int koffB = 0;                                  // current K buffer (bytes)
    for (int it = 0; it < 64; it++) {
        // issue K(it+1) into the other buffer; stays in flight all iteration
        if (it < 63) {
            int m0n = (it + 1) * 16384;             // (it+1)*64 rows * 256 u16
            #pragma unroll
            for (int i = 0; i < 8; i++)
                gll16(ksrc + m0n + i * 2048, ldsKw + (koffB ^ 32768) + i * 4096);
        }

        // S^T[m][q] = K * Q^T   (two 32-row m-tiles) from current K buffer
        int kb = (koffB >> 1) + kb0;
        f32x16 s0, s1;
        #pragma unroll
        for (int i = 0; i < 16; i++) { s0[i] = 0.f; s1[i] = 0.f; }
        __builtin_amdgcn_s_setprio(1);
        #pragma unroll
        for (int ks = 0; ks < 16; ks++) {
            int off = ((ks & 3) == 0 ? tab0 : (ks & 3) == 1 ? tab1
                      : (ks & 3) == 2 ? tab2 : tab3) + (ks >> 2) * 64;
            f16x8 k0 = ldh8(KsU + kb + off);
            s0 = MFMA32(k0, qf[ks], s0);
            f16x8 k1 = ldh8(KsU + kb + 8192 + off);
            s1 = MFMA32(k1, qf[ks], s1);
        }
        __builtin_amdgcn_s_setprio(0);

        // V fragments direct from global (L2): 8 x 16 B per lane.
        // Issued here so ~200cy L2 latency hides under the softmax VALU work.
        const u16* Vit = Vg + it * 64;
        f16x8 vfr[4][2];
        #pragma unroll
        for (int ks = 0; ks < 4; ks++)
            #pragma unroll
            for (int ct = 0; ct < 2; ct++)
                vfr[ks][ct] = ldh8(Vit + (size_t)(ct * 32 + lq) * 4096 + ks * 16 + h * 8);

        // online softmax over m: tree max (depth 5) + one shfl_xor(32)
        float m8[8];
        #pragma unroll
        for (int r = 0; r < 8; r++)
            m8[r] = fmaxf(fmaxf(s0[r], s0[r + 8]), fmaxf(s1[r], s1[r + 8]));
        #pragma unroll
        for (int d = 4; d >= 1; d >>= 1)
            #pragma unroll
            for (int r = 0; r < d; r++) m8[r] = fmaxf(m8[r], m8[r + d]);
        float mt = fmaxf(m8[0], __shfl_xor(m8[0], 32));

        // T13 defer-max: only rescale when some row grew by > 8 nats.
        float mn, al;
        bool resc = !__all(mt - mrow <= 8.0f);
        if (resc) {
            mn = fmaxf(mrow, mt);
            al = EXP2((mrow - mn) * L2E);
            mrow = mn;
        } else {
            mn = mrow;
            al = 1.0f;
        }
        float base = mn * L2E;
        #pragma unroll
        for (int r = 0; r < 16; r++) {
            float p0 = (float)(_Float16)EXP2(__builtin_fmaf(s0[r], L2E, -base));
            float p1 = (float)(_Float16)EXP2(__builtin_fmaf(s1[r], L2E, -base));
            s0[r] = p0; s1[r] = p1;
        }
        float a8[8];
        #pragma unroll
        for (int r = 0; r < 8; r++)
            a8[r] = (s0[r] + s0[r + 8]) + (s1[r] + s1[r + 8]);
        #pragma unroll
        for (int d = 4; d >= 1; d >>= 1)
            #pragma unroll
            for (int r = 0; r < d; r++) a8[r] += a8[r + d];
        float rs = a8[0] + __shfl_xor(a8[0], 32);
        lrow = lrow * al + rs;

        if (resc) {
            #pragma unroll
            for (int r = 0; r < 16; r++) {
                float sc = __shfl(al, 8 * (r >> 2) + 4 * h + (r & 3));
                am[0][r] *= sc; am[1][r] *= sc;
                aq[0][r] *= sc; aq[1][r] *= sc;
            }
        }

        // ---- T12: build PV A-fragments fully in-register ----
        f16x8 pfr[4];
        #pragma unroll
        for (int mt2 = 0; mt2 < 2; mt2++) {
            f32x16 sv = mt2 ? s1 : s0;
            u32 d0 = pk2(sv[0], sv[1]),  d1 = pk2(sv[2], sv[3]);
            u32 d2 = pk2(sv[4], sv[5]),  d3 = pk2(sv[6], sv[7]);
            u32 d4 = pk2(sv[8], sv[9]),  d5 = pk2(sv[10], sv[11]);
            u32 d6 = pk2(sv[12], sv[13]), d7 = pk2(sv[14], sv[15]);
            u32x2 p02 = pl32_swap(d0, d2);
            u32x2 p13 = pl32_swap(d1, d3);
            u32x2 p46 = pl32_swap(d4, d6);
            u32x2 p57 = pl32_swap(d5, d7);
            uint4 fa = {p02.x, p13.x, p02.y, p13.y};
            uint4 fb = {p46.x, p57.x, p46.y, p57.y};
            pfr[mt2 * 2 + 0] = __builtin_bit_cast(f16x8, fa);
            pfr[mt2 * 2 + 1] = __builtin_bit_cast(f16x8, fb);
        }

        // PV: D[q][c] += P*V (am), P*(v^2 hi) + P*(v^2 lo) (aq).
        // v^2 hi/lo computed in-register from the V fragment (exact Dekker).
        __builtin_amdgcn_s_setprio(1);
        #pragma unroll
        for (int ks = 0; ks < 4; ks++) {
            f16x8 pf = pfr[ks];
            #pragma unroll
            for (int ct = 0; ct < 2; ct++) {
                f16x8 vf = vfr[ks][ct];
                am[ct] = MFMA32(pf, vf, am[ct]);
                f16x8 vh = vf * vf;                                  // round(v^2)
                f16x8 vl = __builtin_elementwise_fma(vf, vf, -vh);   // exact residual
                aq[ct] = MFMA32(pf, vh, aq[ct]);
                aq[ct] = MFMA32(pf, vl, aq[ct]);
            }
        }
        __builtin_amdgcn_s_setprio(0);

        // drain K(it+1) writes (issued a full phase ago) + sync; swap buffers
        asm volatile("s_waitcnt vmcnt(0)" ::: "memory");
        __builtin_amdgcn_s_barrier();
        koffB ^= 32768;
    }

    // ---------------- epilogue: out = std * norm(content) + mean ----------
    float inv = 1.0f / lrow;
    float iv[16];
    #pragma unroll
    for (int r = 0; r < 16; r++) iv[r] = __shfl(inv, (r & 3) + 8 * (r >> 2) + 4 * h);
    float* Ms = (float*)smem;                  // [64 c][132 q] f32
    float* Ss = (float*)(smem + 33792);
    #pragma unroll
    for (int ct = 0; ct < 2; ct++)
        #pragma unroll
        for (int rq = 0; rq < 4; rq++) {
            f32x4 mv, sv;
            #pragma unroll
            for (int j = 0; j < 4; j++) {
                int r = 4 * rq + j;
                float mean = am[ct][r] * iv[r];
                float ex2 = aq[ct][r] * iv[r];
                float var = ex2 - mean * mean;
                mv[j] = mean;
                sv[j] = sqrtf(fmaxf(var, 0.f));
            }
            int c = ct * 32 + lq;
            int qloc = w * 32 + 8 * rq + 4 * h;
            *(f32x4*)(Ms + c * 132 + qloc) = mv;
            *(f32x4*)(Ss + c * 132 + qloc) = sv;
        }
    __syncthreads();
    #pragma unroll
    for (int pass = 0; pass < 8; pass++) {
        int c = pass * 8 + (t >> 5);
        int qloc = (t & 31) * 4;
        f32x4 mv = *(const f32x4*)(Ms + c * 132 + qloc);
        f32x4 sv = *(const f32x4*)(Ss + c * 132 + qloc);
        int gc = coff + c;
        size_t basei = ((size_t)b * 256 + gc) * 4096 + q0 + qloc;
        float4 cv = *(const float4*)(content + basei);
        float cmv = cm[b * 256 + gc], crv = cr[b * 256 + gc];
        float4 o;
        o.x = sv[0] * ((cv.x - cmv) * crv) + mv[0];
        o.y = sv[1] * ((cv.y - cmv) * crv) + mv[1];
        o.z = sv[2] * ((cv.z - cmv) * crv) + mv[2];
        o.w = sv[3] * ((cv.w - cmv) * crv) + mv[3];
        *(float4*)(out + basei) = o;
    }
}

// ---------------------------------------------------------------------------
extern "C" void kernel_launch(void* const* d_in, const int* in_sizes, int n_in,
                              void* d_out, int out_size, void* d_ws, size_t ws_size,
                              hipStream_t stream) {
    const float* content = (const float*)d_in[0];
    const float* style   = (const float*)d_in[1];
    const float* ckey    = (const float*)d_in[2];
    const float* skey    = (const float*)d_in[3];
    const float* Wf      = (const float*)d_in[4];
    const float* bfp     = (const float*)d_in[5];
    const float* Wg      = (const float*)d_in[6];
    const float* bgp     = (const float*)d_in[7];
    const float* Wh      = (const float*)d_in[8];
    const float* bhp     = (const float*)d_in[9];
    float* out = (float*)d_out;
    char* ws = (char*)d_ws;

    float* cm = (float*)(ws + 0);               //  4 KiB
    float* cr = (float*)(ws + 4096);            //  4 KiB
    u16*   Wb = (u16*)(ws + 8192);              //  384 KiB
    u16*   A  = (u16*)(ws + 1048576);           //  8 MiB: Qt
    u16*   Bv = (u16*)(ws + 9437184);           //  8 MiB: Vt [c][tok]
    u16*   Cc = (u16*)(ws + 17825792);          //  8 MiB: Xk -> Kt
    u16*   X1 = (u16*)d_out;                    //  8 MiB scratch (style^T)
    u16*   X2 = (u16*)d_out + 4194304;          //  8 MiB scratch (ckey^T)

    k_stats<<<dim3(1024), 256, 0, stream>>>(content, cm, cr);
    k_prep<<<dim3(64, 4, 15), 256, 0, stream>>>(style, ckey, skey, Wf, Wg, Wh,
                                                X1, X2, Cc, Wb);
    k_gemm<<<dim3(32, 4, 3), 256, 0, stream>>>(X1, X2, Cc, A, Bv, Wb, bfp, bgp, bhp);
    k_flash<<<dim3(32, 4, 4), 256, 0, stream>>>(A, Cc, Bv, content, cm, cr, out);
}